// Round 10
// baseline (407.567 us; speedup 1.0000x reference)
//
#include <hip/hip_runtime.h>
#include <hip/hip_bf16.h>
#include <math.h>

#define S_ 4
#define N_ 4096
#define M_ 4096
#define D_ 128
#define BN_ 128            // anchors per block
#define CH_ 4              // m-chunks per stem
#define MCH_ (M_ / CH_)    // 1024 m per chunk
#define NST_ (MCH_ / 64)   // 16 stages of 64 m
#define LN2_ 0.69314718055994531f
#define LOG2E_ 1.44269504088896340f

typedef __bf16 bf16x8 __attribute__((ext_vector_type(8)));
typedef float f32x4 __attribute__((ext_vector_type(4)));

// async global->LDS, 16B per lane (dest = wave-uniform base + lane*16)
__device__ __forceinline__ void gll16(const void* g, void* l) {
    __builtin_amdgcn_global_load_lds(
        (const __attribute__((address_space(1))) unsigned int*)g,
        (__attribute__((address_space(3))) unsigned int*)l, 16, 0, 0);
}

// RNE float -> bf16 bits
__device__ __forceinline__ unsigned short f2bf(float f) {
    unsigned u = __float_as_uint(f);
    unsigned r = (u + 0x7FFFu + ((u >> 16) & 1u)) >> 16;
    return (unsigned short)r;
}

// ---------------- Phase 1: L2-normalize art AND ref rows, write bf16 ----------------
__global__ void nrm_rows_kernel(const float* __restrict__ art, const float* __restrict__ ref,
                                unsigned short* __restrict__ an, unsigned short* __restrict__ rn) {
    const int w = threadIdx.x >> 6;
    const int lane = threadIdx.x & 63;
    const int half = lane >> 5;
    const int li = lane & 31;
    const int row = blockIdx.x * 8 + w * 2 + half;   // 0 .. S_*(N_+M_)-1
    const bool is_art = row < S_ * N_;
    const float* src = is_art ? (art + (size_t)row * D_)
                              : (ref + (size_t)(row - S_ * N_) * D_);
    unsigned short* dst = is_art ? (an + (size_t)row * D_)
                                 : (rn + (size_t)(row - S_ * N_) * D_);
    const float4 v = *reinterpret_cast<const float4*>(src + li * 4);
    float ss = v.x * v.x + v.y * v.y + v.z * v.z + v.w * v.w;
#pragma unroll
    for (int off = 1; off < 32; off <<= 1) ss += __shfl_xor(ss, off);
    const float scale = 1.0f / fmaxf(sqrtf(ss), 1e-12f);
    uint2 pack;
    pack.x = (unsigned)f2bf(v.x * scale) | ((unsigned)f2bf(v.y * scale) << 16);
    pack.y = (unsigned)f2bf(v.z * scale) | ((unsigned)f2bf(v.w * scale) << 16);
    *reinterpret_cast<uint2*>(dst + li * 4) = pack;
}

// 4 values -> 4 mask bits
__device__ __forceinline__ unsigned nib4(int a, int b, int c, int d) {
    return (unsigned)((a != 0) | ((b != 0) << 1) | ((c != 0) << 2) | ((d != 0) << 3));
}
__device__ __forceinline__ unsigned nib_bytes(unsigned b) {   // 4 bool bytes -> 4 bits
    return ((b & 0xFFu) ? 1u : 0u) | ((b & 0xFF00u) ? 2u : 0u)
         | ((b & 0xFF0000u) ? 4u : 0u) | ((b & 0xFF000000u) ? 8u : 0u);
}

// lane covers 32 consecutive mask elements; returns 8 nibbles packed in a u32
template <int ESZ>
__device__ __forceinline__ void mload(int4* mq, const unsigned char* p) {
    if (ESZ == 4) {
#pragma unroll
        for (int j = 0; j < 8; ++j) mq[j] = *reinterpret_cast<const int4*>(p + j * 16);
    } else {
        mq[0] = *reinterpret_cast<const int4*>(p);
        mq[1] = *reinterpret_cast<const int4*>(p + 16);
    }
}
template <int ESZ>
__device__ __forceinline__ unsigned mconv(const int4* mq) {
    unsigned u = 0;
    if (ESZ == 4) {
#pragma unroll
        for (int j = 0; j < 8; ++j)
            u |= nib4(mq[j].x, mq[j].y, mq[j].z, mq[j].w) << (4 * j);
    } else {
#pragma unroll
        for (int k = 0; k < 2; ++k) {
            u |= nib_bytes((unsigned)mq[k].x) << ((k * 4 + 0) * 4);
            u |= nib_bytes((unsigned)mq[k].y) << ((k * 4 + 1) * 4);
            u |= nib_bytes((unsigned)mq[k].z) << ((k * 4 + 2) * 4);
            u |= nib_bytes((unsigned)mq[k].w) << ((k * 4 + 3) * 4);
        }
    }
    return u;
}

// ---------------- Phase 2 body (templated on mask element size) ----------------
// Block: BN_=128 anchors x 1024 m. 512 blocks, 2/CU. Wave w owns anchors [w*32, w*32+32).
// Per 64-m stage: rn tile 16KB via global_load_lds (XOR-swizzled source, linear LDS dest);
// mask bits: lane-pair per row loads int4-vectorized elements for stage st+1, converts to
// a u64/row nibble table in LDS. Fixed-offset exp2 (C = 0.5*scale2): no online max at all —
// logits bounded by |cos|<=1, so exp2(l - C) never overflows and dominant terms never
// underflow; C cancels in den - num. Partials are plain sums.
template <int ESZ>
__device__ __forceinline__ void run_main(
    const unsigned short* __restrict__ an, const unsigned short* __restrict__ rn,
    const unsigned char* __restrict__ maskb, float scale2, float4* __restrict__ part4,
    int s, int ch, int n_base,
    unsigned char (&smem)[2][64 * 256], unsigned long long (&mtab)[2][BN_]) {

    const int tid = threadIdx.x;
    const int w = tid >> 6;
    const int lane = tid & 63;
    const int lrow = lane & 15;        // anchor col within 16-group
    const int lgrp = lane >> 4;        // k-group / m-row group
    const float negC = -0.5f * scale2;

    // art fragments: 2 n-subtiles of 16 anchors each
    bf16x8 bfr[2][4];
#pragma unroll
    for (int nc = 0; nc < 2; ++nc) {
        const unsigned short* abase =
            an + ((size_t)(s * N_ + n_base + w * 32 + nc * 16 + lrow)) * D_ + lgrp * 8;
#pragma unroll
        for (int kc = 0; kc < 4; ++kc)
            bfr[nc][kc] = *reinterpret_cast<const bf16x8*>(abase + kc * 32);
    }

    // rn staging: thread covers row srow (+j*16), 16B chunk (lane&15), source XOR-swizzled
    const int srow = w * 4 + (lane >> 4);
    const int schunk = (lane & 15) ^ (srow & 7);
    const int lane_src_off = srow * 256 + schunk * 16;
    const unsigned char* rn_chunk =
        (const unsigned char*)(rn + ((size_t)(s * M_ + ch * MCH_)) * D_);

    // mask: lane covers row w*32 + (lane>>1), elements h*32..h*32+31 of each 64-m stage
    const int mrow = w * 32 + (lane >> 1);
    const int h = lane & 1;
    const unsigned char* mbase = maskb +
        ((size_t)(s * N_ + n_base + mrow) * M_ + (size_t)(ch * MCH_ + h * 32)) * ESZ;

    float dsum0 = 0.f, dsum1 = 0.f, nsum0 = 0.f, nsum1 = 0.f;
    int npos0 = 0, npos1 = 0;
    int4 mq[ESZ == 4 ? 8 : 2];

    // ---- prologue: rn stage 0; mask stage 0 (load+convert) and stage 1 (in flight) ----
    {
        const unsigned char* src = rn_chunk + lane_src_off;
        unsigned char* dst = &smem[0][w * 1024];
#pragma unroll
        for (int j = 0; j < 4; ++j) gll16(src + j * 4096, dst + j * 4096);
        mload<ESZ>(mq, mbase);
        reinterpret_cast<unsigned*>(&mtab[0][mrow])[h] = mconv<ESZ>(mq);
        mload<ESZ>(mq, mbase + (size_t)64 * ESZ);
        __syncthreads();
    }

    for (int st = 0; st < NST_; ++st) {
        const int buf = st & 1;
        if (st + 1 < NST_) {
            // rn prefetch for st+1
            const unsigned char* src = rn_chunk + (size_t)(st + 1) * 16384 + lane_src_off;
            unsigned char* dst = &smem[buf ^ 1][w * 1024];
#pragma unroll
            for (int j = 0; j < 4; ++j) gll16(src + j * 4096, dst + j * 4096);
            // convert mask bits for st+1 (loaded last stage)
            reinterpret_cast<unsigned*>(&mtab[buf ^ 1][mrow])[h] = mconv<ESZ>(mq);
        }
        if (st + 2 < NST_) mload<ESZ>(mq, mbase + (size_t)(st + 2) * 64 * ESZ);

        // ---- 32 MFMA from LDS (4 m-tiles x 2 n-subtiles x 4 K-chunks) ----
        const unsigned char* base_ = &smem[buf][0];
        f32x4 acc[4][2] = {};
#pragma unroll
        for (int mt = 0; mt < 4; ++mt) {
            const int rowb = (mt * 16 + lrow) * 256;
#pragma unroll
            for (int kc = 0; kc < 4; ++kc) {
                const bf16x8 af = *reinterpret_cast<const bf16x8*>(
                    base_ + rowb + (((kc * 4 + lgrp) ^ (lrow & 7)) * 16));
                acc[mt][0] = __builtin_amdgcn_mfma_f32_16x16x32_bf16(af, bfr[0][kc], acc[mt][0], 0, 0, 0);
                acc[mt][1] = __builtin_amdgcn_mfma_f32_16x16x32_bf16(af, bfr[1][kc], acc[mt][1], 0, 0, 0);
            }
        }
        // ---- epilogue: fixed-offset exp2, plain sums ----
        const unsigned long long w0 = mtab[buf][w * 32 + lrow];
        const unsigned long long w1 = mtab[buf][w * 32 + 16 + lrow];
        float d0 = 0.f, d1 = 0.f, n0 = 0.f, n1 = 0.f;
#pragma unroll
        for (int mt = 0; mt < 4; ++mt) {
            const unsigned nib0 = (unsigned)(w0 >> ((mt * 4 + lgrp) * 4)) & 0xFu;
            const unsigned nib1 = (unsigned)(w1 >> ((mt * 4 + lgrp) * 4)) & 0xFu;
            float e0[4], e1[4];
#pragma unroll
            for (int i = 0; i < 4; ++i) {
                e0[i] = exp2f(fmaf(acc[mt][0][i], scale2, negC));
                e1[i] = exp2f(fmaf(acc[mt][1][i], scale2, negC));
            }
            d0 += (e0[0] + e0[1]) + (e0[2] + e0[3]);
            d1 += (e1[0] + e1[1]) + (e1[2] + e1[3]);
            n0 += (((nib0 & 1u) ? e0[0] : 0.f) + (((nib0 >> 1) & 1u) ? e0[1] : 0.f))
                + ((((nib0 >> 2) & 1u) ? e0[2] : 0.f) + (((nib0 >> 3) & 1u) ? e0[3] : 0.f));
            n1 += (((nib1 & 1u) ? e1[0] : 0.f) + (((nib1 >> 1) & 1u) ? e1[1] : 0.f))
                + ((((nib1 >> 2) & 1u) ? e1[2] : 0.f) + (((nib1 >> 3) & 1u) ? e1[3] : 0.f));
            npos0 += __popc(nib0);
            npos1 += __popc(nib1);
        }
        dsum0 += d0; dsum1 += d1; nsum0 += n0; nsum1 += n1;
        __syncthreads();
    }

    // merge lgrp groups (same anchors, different m): plain shuffle-adds
    float npf0 = (float)npos0, npf1 = (float)npos1;
#pragma unroll
    for (int off = 16; off < 64; off <<= 1) {
        dsum0 += __shfl_xor(dsum0, off); dsum1 += __shfl_xor(dsum1, off);
        nsum0 += __shfl_xor(nsum0, off); nsum1 += __shfl_xor(nsum1, off);
        npf0  += __shfl_xor(npf0, off);  npf1  += __shfl_xor(npf1, off);
    }
    if (lane < 16) {
        const int ag0 = s * N_ + n_base + w * 32 + lane;
        part4[ag0 * CH_ + ch] = make_float4(dsum0, nsum0, npf0, 0.f);
        part4[(ag0 + 16) * CH_ + ch] = make_float4(dsum1, nsum1, npf1, 0.f);
    }
}

// ---------------- Phase 2: dispatcher kernel ----------------
__global__ __launch_bounds__(256, 2) void infonce_main_kernel(
    const unsigned short* __restrict__ an, const unsigned short* __restrict__ rn,
    const unsigned char* __restrict__ maskb, const float* __restrict__ logtemp,
    float4* __restrict__ part4) {

    const int bid = blockIdx.x;
    const int swz = (bid & 7) * 64 + (bid >> 3);   // 512 % 8 == 0 -> bijective
    const int ch = swz >> 7;                       // 0..3
    const int s = (swz >> 5) & 3;                  // 0..3
    const int n_base = (swz & 31) * BN_;
    const float scale2 = __expf(-logtemp[0]) * LOG2E_;   // 1/(temp*ln2)

    // mask dtype detection over 1 KB: byte-packed bools seen as u32 show values > 1
    const unsigned* mu = (const unsigned*)maskb;
    unsigned pr = 0;
#pragma unroll
    for (int i = 0; i < 4; ++i) pr |= (mu[i * 64 + (threadIdx.x & 63)] > 1u) ? 1u : 0u;
    const bool byte_mode = (__ballot(pr != 0) != 0ull);

    __shared__ unsigned char smem[2][64 * 256];     // 2 x 16 KB rn stage buffers
    __shared__ unsigned long long mtab[2][BN_];     // nibble table: 64 mask bits per row

    if (byte_mode)
        run_main<1>(an, rn, maskb, scale2, part4, s, ch, n_base, smem, mtab);
    else
        run_main<4>(an, rn, maskb, scale2, part4, s, ch, n_base, smem, mtab);
}

// ---------------- Phase 3: merge chunk partials -> per-block (pa,cnt) partial ----------------
__global__ void reduce_kernel(const float4* __restrict__ part4, float2* __restrict__ bpart) {
    const int a = blockIdx.x * 256 + threadIdx.x;   // anchor
    const int w = threadIdx.x >> 6;
    const int lane = threadIdx.x & 63;
    float ds = 0.f, ns = 0.f, npf = 0.f;
#pragma unroll
    for (int ch = 0; ch < CH_; ++ch) {
        const float4 p = part4[a * CH_ + ch];
        ds += p.x; ns += p.y; npf += p.z;
    }
    const bool valid = (npf > 0.5f) && (npf < (float)M_ - 0.5f);
    float pa = valid ? LN2_ * (log2f(ds) - log2f(ns)) : 0.f;
    float cv = valid ? 1.f : 0.f;
#pragma unroll
    for (int off = 1; off < 64; off <<= 1) {
        pa += __shfl_xor(pa, off);
        cv += __shfl_xor(cv, off);
    }
    __shared__ float sp[4], sc[4];
    if (lane == 0) { sp[w] = pa; sc[w] = cv; }
    __syncthreads();
    if (threadIdx.x == 0)
        bpart[blockIdx.x] = make_float2(sp[0] + sp[1] + sp[2] + sp[3],
                                        sc[0] + sc[1] + sc[2] + sc[3]);
}

// ---------------- Phase 4: finalize (64 block-partials, 16 per stem) ----------------
__global__ void finalize_kernel(const float2* __restrict__ bpart, float* __restrict__ out) {
    const int t = threadIdx.x;   // 64 threads
    const float2 v = bpart[t];
    float pa = v.x, cv = v.y;
#pragma unroll
    for (int off = 1; off < 16; off <<= 1) {
        pa += __shfl_xor(pa, off);
        cv += __shfl_xor(cv, off);
    }
    const float p0 = __shfl(pa, 0),  c0 = __shfl(cv, 0);
    const float p1 = __shfl(pa, 16), c1 = __shfl(cv, 16);
    const float p2 = __shfl(pa, 32), c2 = __shfl(cv, 32);
    const float p3 = __shfl(pa, 48), c3 = __shfl(cv, 48);
    if (t == 0) {
        float total = 0.f;
        int scnt = 0;
        const float ps[4] = {p0, p1, p2, p3};
        const float cs[4] = {c0, c1, c2, c3};
        for (int s = 0; s < S_; ++s) {
            const float stem = ps[s] / fmaxf(cs[s], 1.f);
            if (cs[s] > 0.f) { total += stem; scnt++; }
        }
        out[0] = total / (float)(scnt > 0 ? scnt : 1);
    }
}

extern "C" void kernel_launch(void* const* d_in, const int* in_sizes, int n_in,
                              void* d_out, int out_size, void* d_ws, size_t ws_size,
                              hipStream_t stream) {
    const float* art = (const float*)d_in[0];
    const float* ref = (const float*)d_in[1];
    const unsigned char* mask = (const unsigned char*)d_in[2];
    const float* lt = (const float*)d_in[3];
    float* out = (float*)d_out;

    char* ws = (char*)d_ws;
    unsigned short* an = (unsigned short*)ws;                       // 4 MB
    unsigned short* rn = (unsigned short*)(ws + (size_t)4194304);   // 4 MB
    float4* part4 = (float4*)(ws + (size_t)8388608);                // 1 MB
    float2* bpart = (float2*)(ws + (size_t)9437184);                // 512 B

    nrm_rows_kernel<<<(S_ * (N_ + M_)) / 8, 256, 0, stream>>>(art, ref, an, rn);
    infonce_main_kernel<<<S_ * (N_ / BN_) * CH_, 256, 0, stream>>>(an, rn, mask, lt, part4);
    reduce_kernel<<<(S_ * N_) / 256, 256, 0, stream>>>(part4, bpart);
    finalize_kernel<<<1, 64, 0, stream>>>(bpart, out);
}